// Round 4
// baseline (9352.428 us; speedup 1.0000x reference)
//
#include <hip/hip_runtime.h>
#include <math.h>
#include <stdint.h>

// Problem constants (fixed by the reference)
#define N_NODES 16384
#define HID 512
#define G4 2048   // 4*HID
#define MAXC 4

// Dataflow config: 16 teams x 16 slices (wgs), 512 threads each. grid = 256
// == #CUs -> all wgs co-resident; teams claim nodes in increasing index order
// -> smallest-unfinished-node argument gives deadlock freedom.
#define T_TEAMS 16
#define S_WGS 16
#define NWG 256
#define BLK 512            // threads per wg (8 waves)
#define NSUB 16            // e-chunks per wg
#define ECH 32             // e's per chunk  (NSUB*ECH = 512)

#define SENT 0xFFFFFFFFu   // NaN bit pattern used as "not yet written" sentinel

#define AT_LDF(p)   __hip_atomic_load((p), __ATOMIC_RELAXED, __HIP_MEMORY_SCOPE_AGENT)
#define AT_LDU(p)   __hip_atomic_load((p), __ATOMIC_RELAXED, __HIP_MEMORY_SCOPE_AGENT)
#define AT_STF(p,v) __hip_atomic_store((p), (v), __ATOMIC_RELAXED, __HIP_MEMORY_SCOPE_AGENT)

__device__ __forceinline__ float sigm(float x) { return 1.0f / (1.0f + __expf(-x)); }

// ---------------------------------------------------------------------------
// Kernel 1: i2h = inputs @ i2h_weight^T + i2h_bias (unchanged — correct)
// ---------------------------------------------------------------------------
#define BK 16
__global__ void __launch_bounds__(256) gemm_i2h(
    const float* __restrict__ A, const float* __restrict__ B,
    const float* __restrict__ bias, float* __restrict__ C)
{
  __shared__ float As[BK][68];
  __shared__ float Bs[BK][68];
  const int tid = threadIdx.x;
  const int tx = tid & 15, ty = tid >> 4;
  const int rowBase = blockIdx.y * 64, colBase = blockIdx.x * 64;
  const int r = tid >> 2;
  const int kk = (tid & 3) << 2;
  float acc[4][4] = {};

  for (int k0 = 0; k0 < 512; k0 += BK) {
    float4 a4 = *(const float4*)&A[(size_t)(rowBase + r) * 512 + k0 + kk];
    float4 b4 = *(const float4*)&B[(size_t)(colBase + r) * 512 + k0 + kk];
    __syncthreads();
    As[kk + 0][r] = a4.x; As[kk + 1][r] = a4.y; As[kk + 2][r] = a4.z; As[kk + 3][r] = a4.w;
    Bs[kk + 0][r] = b4.x; Bs[kk + 1][r] = b4.y; Bs[kk + 2][r] = b4.z; Bs[kk + 3][r] = b4.w;
    __syncthreads();
#pragma unroll
    for (int k = 0; k < BK; k++) {
      float4 av = *(const float4*)&As[k][ty << 2];
      float4 bv = *(const float4*)&Bs[k][tx << 2];
      float a0 = av.x, a1 = av.y, a2 = av.z, a3 = av.w;
      float b0 = bv.x, b1 = bv.y, b2 = bv.z, b3 = bv.w;
      acc[0][0] += a0 * b0; acc[0][1] += a0 * b1; acc[0][2] += a0 * b2; acc[0][3] += a0 * b3;
      acc[1][0] += a1 * b0; acc[1][1] += a1 * b1; acc[1][2] += a1 * b2; acc[1][3] += a1 * b3;
      acc[2][0] += a2 * b0; acc[2][1] += a2 * b1; acc[2][2] += a2 * b2; acc[2][3] += a2 * b3;
      acc[3][0] += a3 * b0; acc[3][1] += a3 * b1; acc[3][2] += a3 * b2; acc[3][3] += a3 * b3;
    }
  }
#pragma unroll
  for (int i = 0; i < 4; i++) {
    const int row = rowBase + (ty << 2) + i;
    const int col = colBase + (tx << 2);
    float4 o;
    o.x = acc[i][0] + bias[col + 0];
    o.y = acc[i][1] + bias[col + 1];
    o.z = acc[i][2] + bias[col + 2];
    o.w = acc[i][3] + bias[col + 3];
    *(float4*)&C[(size_t)row * G4 + col] = o;
  }
}

// ---------------------------------------------------------------------------
// Gate dot-products: weights in registers/L1, child h from LDS (broadcast).
// ---------------------------------------------------------------------------
template<int NC>
__device__ __forceinline__ void gates_lds(
    const float (*hch)[HID], int e0,
    const float4* wi, const float4* wu, const float4* wo, const float* wf,
    float& aI, float& aU, float& aO, float (&aF)[4])
{
#pragma unroll
  for (int q = 0; q < 8; q++) {
    float4 c0 = *(const float4*)&hch[0][e0 + 4 * q];
    float4 c1 = {0,0,0,0}, c2 = {0,0,0,0}, c3 = {0,0,0,0};
    if constexpr (NC > 1) c1 = *(const float4*)&hch[1][e0 + 4 * q];
    if constexpr (NC > 2) c2 = *(const float4*)&hch[2][e0 + 4 * q];
    if constexpr (NC > 3) c3 = *(const float4*)&hch[3][e0 + 4 * q];
    float sx = c0.x, sy = c0.y, sz = c0.z, sw = c0.w;
    if constexpr (NC > 1) { sx += c1.x; sy += c1.y; sz += c1.z; sw += c1.w; }
    if constexpr (NC > 2) { sx += c2.x; sy += c2.y; sz += c2.z; sw += c2.w; }
    if constexpr (NC > 3) { sx += c3.x; sy += c3.y; sz += c3.z; sw += c3.w; }
    aI += wi[q].x * sx; aI += wi[q].y * sy; aI += wi[q].z * sz; aI += wi[q].w * sw;
    aU += wu[q].x * sx; aU += wu[q].y * sy; aU += wu[q].z * sz; aU += wu[q].w * sw;
    aO += wo[q].x * sx; aO += wo[q].y * sy; aO += wo[q].z * sz; aO += wo[q].w * sw;
    aF[0] += wf[4*q+0] * c0.x; aF[0] += wf[4*q+1] * c0.y;
    aF[0] += wf[4*q+2] * c0.z; aF[0] += wf[4*q+3] * c0.w;
    if constexpr (NC > 1) {
      aF[1] += wf[4*q+0] * c1.x; aF[1] += wf[4*q+1] * c1.y;
      aF[1] += wf[4*q+2] * c1.z; aF[1] += wf[4*q+3] * c1.w;
    }
    if constexpr (NC > 2) {
      aF[2] += wf[4*q+0] * c2.x; aF[2] += wf[4*q+1] * c2.y;
      aF[2] += wf[4*q+2] * c2.z; aF[2] += wf[4*q+3] * c2.w;
    }
    if constexpr (NC > 3) {
      aF[3] += wf[4*q+0] * c3.x; aF[3] += wf[4*q+1] * c3.y;
      aF[3] += wf[4*q+2] * c3.z; aF[3] += wf[4*q+3] * c3.w;
    }
  }
}

// ---------------------------------------------------------------------------
// Kernel 2: persistent dataflow recurrence, flag-free.
// Readiness IS the data: H is NaN-initialized (0xFF memset); consumers
// spin-load H[child][tid] (relaxed agent scope, LLC-coherent, coalesced)
// until non-sentinel — detect and fetch are the same round trip.
// Producer order: C stores -> s_waitcnt(0) -> H stores, per slice-wg; the
// consumer thread needing C[child][d] polls H[child][d] from the SAME
// producer wg, so C is always visible once its H is.
// Barriers: 2 per non-leaf node, 0 per leaf. Next-node polling overlaps the
// previous node's wave0 epilogue.
// ---------------------------------------------------------------------------
__global__ void __launch_bounds__(BLK, 2) recur(
    const float* __restrict__ i2h,
    const float* __restrict__ hs2h_w, const float* __restrict__ hc2h_w,
    const float* __restrict__ hs2h_b, const float* __restrict__ hc2h_b,
    const int* __restrict__ child_idx, const int* __restrict__ child_mask,
    float* Hout, float* Cout)
{
  __shared__ float hch[MAXC][HID];     // 8 KB: children h
  __shared__ float chc[MAXC][32];      // 0.5 KB: children c (this slice only)
  __shared__ float4 redA[NSUB][32];    // 8 KB: {aI,aU,aO,aF0}
  __shared__ float4 redB[NSUB][32];    // 8 KB: {aF1,aF2,aF3,-}

  const int tid = threadIdx.x;
  const int wg = blockIdx.x;
  const int team = wg & (T_TEAMS - 1);
  const int slice = wg >> 4;           // 0..15 : this wg's 32 hidden dims
  const int rr = tid & 31;
  const int sub = tid >> 5;            // 0..15 : e-chunk
  const int rp = slice * 32 + rr;
  const int e0 = sub * ECH;
  const int lr = tid - slice * 32;     // 0..31 iff this thread stages our c-slice

  // ---- one-time: weights (compiler keeps hot in regs/L1) ----
  float4 wi[8], wu[8], wo[8];
  float wf[32];
#pragma unroll
  for (int q = 0; q < 8; q++) {
    wi[q] = *(const float4*)&hs2h_w[(size_t)rp * HID + e0 + 4 * q];
    wu[q] = *(const float4*)&hs2h_w[(size_t)(512 + rp) * HID + e0 + 4 * q];
    wo[q] = *(const float4*)&hs2h_w[(size_t)(1024 + rp) * HID + e0 + 4 * q];
  }
#pragma unroll
  for (int e = 0; e < 32; e++)
    wf[e] = hc2h_w[(size_t)(e0 + e) * HID + rp];

  // ---- one-time: epilogue biases (wave0 / tid<32 only) ----
  const int rpp = slice * 32 + tid;    // valid only for tid<32
  float bI = 0.f, bU = 0.f, bO = 0.f, bF = 0.f;
  if (tid < 32) {
    bI = hs2h_b[rpp]; bU = hs2h_b[512 + rpp];
    bO = hs2h_b[1024 + rpp]; bF = hc2h_b[rpp];
  }

  for (int j = team; j < N_NODES; j += T_TEAMS) {
    const int4 ci = *(const int4*)&child_idx[j * 4];
    const int4 cm = *(const int4*)&child_mask[j * 4];
    const int nc = cm.x + cm.y + cm.z + cm.w;   // mask is a prefix
    const int cix[4] = {ci.x, ci.y, ci.z, ci.w};

    // prefetch i2h (plain cached loads; overlaps everything below)
    float ipre = 0.f, fpre = 0.f, upre = 0.f, opre = 0.f;
    if (tid < 32) {
      const size_t jb = (size_t)j * G4;
      ipre = i2h[jb + rpp];
      fpre = i2h[jb + 512 + rpp];
      upre = i2h[jb + 1024 + rpp];
      opre = i2h[jb + 1536 + rpp];
    }

    float aI = 0.f, aU = 0.f, aO = 0.f, aF[4] = {0.f, 0.f, 0.f, 0.f};

    if (nc > 0) {
      // ---- fused poll + stage: spin until H[child][tid] != sentinel ----
#pragma unroll
      for (int k = 0; k < MAXC; k++) {
        if (k < nc) {
          const uint32_t* hp = (const uint32_t*)(Hout + (size_t)cix[k] * HID + tid);
          uint32_t v = AT_LDU(hp);
          while (v == SENT) { __builtin_amdgcn_s_sleep(1); v = AT_LDU(hp); }
          hch[k][tid] = __uint_as_float(v);
          // our slice of child's C was drained before its H by the same
          // producer wg -> visible now
          if ((unsigned)lr < 32u)
            chc[k][lr] = AT_LDF(Cout + (size_t)cix[k] * HID + tid);
        }
      }
      __syncthreads();  // B2: hch/chc ready

      // wave0 snapshots child c before B3 (stage of next node rewrites chc)
      float cC0 = 0.f, cC1 = 0.f, cC2 = 0.f, cC3 = 0.f;
      if (tid < 32) {
        cC0 = chc[0][tid];
        if (nc > 1) cC1 = chc[1][tid];
        if (nc > 2) cC2 = chc[2][tid];
        if (nc > 3) cC3 = chc[3][tid];
      }

      switch (nc) {
        case 1: gates_lds<1>(hch, e0, wi, wu, wo, wf, aI, aU, aO, aF); break;
        case 2: gates_lds<2>(hch, e0, wi, wu, wo, wf, aI, aU, aO, aF); break;
        case 3: gates_lds<3>(hch, e0, wi, wu, wo, wf, aI, aU, aO, aF); break;
        default: gates_lds<4>(hch, e0, wi, wu, wo, wf, aI, aU, aO, aF); break;
      }
      redA[sub][rr] = make_float4(aI, aU, aO, aF[0]);
      redB[sub][rr] = make_float4(aF[1], aF[2], aF[3], 0.f);
      __syncthreads();  // B3: red ready; hch free for next node

      if (tid < 32) {
        float sI = 0.f, sU = 0.f, sO = 0.f;
        float sF0 = 0.f, sF1 = 0.f, sF2 = 0.f, sF3 = 0.f;
#pragma unroll
        for (int s = 0; s < NSUB; s++) {
          float4 a = redA[s][tid];
          float4 b = redB[s][tid];
          sI += a.x; sU += a.y; sO += a.z; sF0 += a.w;
          sF1 += b.x; sF2 += b.y; sF3 += b.z;
        }
        const float ig = ipre + bI + sI;
        const float ug = upre + bU + sU;
        const float og = opre + bO + sO;
        float c = sigm(ig) * tanhf(ug);
        c += sigm(fpre + bF + sF0) * cC0;
        if (nc > 1) c += sigm(fpre + bF + sF1) * cC1;
        if (nc > 2) c += sigm(fpre + bF + sF2) * cC2;
        if (nc > 3) c += sigm(fpre + bF + sF3) * cC3;
        const float h = sigm(og) * tanhf(c);
        AT_STF(Cout + (size_t)j * HID + rpp, c);
        asm volatile("" ::: "memory");
        __builtin_amdgcn_s_waitcnt(0);   // C visible at LLC before H store
        asm volatile("" ::: "memory");
        AT_STF(Hout + (size_t)j * HID + rpp, h);
      }
    } else {
      // leaf: no children, no barriers
      if (tid < 32) {
        const float ig = ipre + bI;
        const float ug = upre + bU;
        const float og = opre + bO;
        const float c = sigm(ig) * tanhf(ug);
        const float h = sigm(og) * tanhf(c);
        AT_STF(Cout + (size_t)j * HID + rpp, c);
        asm volatile("" ::: "memory");
        __builtin_amdgcn_s_waitcnt(0);
        asm volatile("" ::: "memory");
        AT_STF(Hout + (size_t)j * HID + rpp, h);
      }
    }
  }
}

// ---------------------------------------------------------------------------
// Workspace: [0,128MB) i2h. No flags — H itself is the readiness signal.
// ---------------------------------------------------------------------------
extern "C" void kernel_launch(void* const* d_in, const int* in_sizes, int n_in,
                              void* d_out, int out_size, void* d_ws, size_t ws_size,
                              hipStream_t stream) {
  const float* inputs    = (const float*)d_in[0];
  const float* i2h_w     = (const float*)d_in[1];
  const float* i2h_b     = (const float*)d_in[2];
  const float* hs2h_w    = (const float*)d_in[3];
  const float* hs2h_b    = (const float*)d_in[4];
  const float* hc2h_w    = (const float*)d_in[5];
  const float* hc2h_b    = (const float*)d_in[6];
  const int*   child_idx = (const int*)d_in[7];
  const int*   child_mask= (const int*)d_in[8];

  float* Hout = (float*)d_out;
  float* Cout = Hout + (size_t)N_NODES * HID;

  float* i2h = (float*)d_ws;

  // H region -> 0xFFFFFFFF = NaN sentinel (computed h is always finite)
  hipMemsetAsync(Hout, 0xFF, (size_t)N_NODES * HID * sizeof(float), stream);

  dim3 ggrid(G4 / 64, N_NODES / 64);
  gemm_i2h<<<ggrid, 256, 0, stream>>>(inputs, i2h_w, i2h_b, i2h);
  recur<<<NWG, BLK, 0, stream>>>(i2h, hs2h_w, hc2h_w, hs2h_b, hc2h_b,
                                 child_idx, child_mask, Hout, Cout);
}

// Round 5
// 8993.102 us; speedup vs baseline: 1.0400x; 1.0400x over previous
//
#include <hip/hip_runtime.h>
#include <math.h>
#include <stdint.h>

// Problem constants (fixed by the reference)
#define N_NODES 16384
#define HID 512
#define G4 2048   // 4*HID
#define MAXC 4

// Dataflow config: 16 teams x 16 slices (wgs), 512 threads each. grid = 256
// == #CUs -> all wgs co-resident; teams claim nodes in increasing index order
// -> smallest-unfinished-node argument gives deadlock freedom.
#define T_TEAMS 16
#define S_WGS 16
#define NWG 256
#define BLK 512            // threads per wg (8 waves)
#define NSUB 16            // e-chunks per wg
#define ECH 32             // e's per chunk  (NSUB*ECH = 512)

#define SENT 0xFFFFFFFFu   // NaN bit pattern = "not yet written" (h,c always finite)

#define AT_LDU(p)   __hip_atomic_load((p), __ATOMIC_RELAXED, __HIP_MEMORY_SCOPE_AGENT)
#define AT_STF(p,v) __hip_atomic_store((p), (v), __ATOMIC_RELAXED, __HIP_MEMORY_SCOPE_AGENT)

__device__ __forceinline__ float sigm(float x) { return 1.0f / (1.0f + __expf(-x)); }

// ---------------------------------------------------------------------------
// Kernel 1: i2h = inputs @ i2h_weight^T + i2h_bias (unchanged — correct)
// ---------------------------------------------------------------------------
#define BK 16
__global__ void __launch_bounds__(256) gemm_i2h(
    const float* __restrict__ A, const float* __restrict__ B,
    const float* __restrict__ bias, float* __restrict__ C)
{
  __shared__ float As[BK][68];
  __shared__ float Bs[BK][68];
  const int tid = threadIdx.x;
  const int tx = tid & 15, ty = tid >> 4;
  const int rowBase = blockIdx.y * 64, colBase = blockIdx.x * 64;
  const int r = tid >> 2;
  const int kk = (tid & 3) << 2;
  float acc[4][4] = {};

  for (int k0 = 0; k0 < 512; k0 += BK) {
    float4 a4 = *(const float4*)&A[(size_t)(rowBase + r) * 512 + k0 + kk];
    float4 b4 = *(const float4*)&B[(size_t)(colBase + r) * 512 + k0 + kk];
    __syncthreads();
    As[kk + 0][r] = a4.x; As[kk + 1][r] = a4.y; As[kk + 2][r] = a4.z; As[kk + 3][r] = a4.w;
    Bs[kk + 0][r] = b4.x; Bs[kk + 1][r] = b4.y; Bs[kk + 2][r] = b4.z; Bs[kk + 3][r] = b4.w;
    __syncthreads();
#pragma unroll
    for (int k = 0; k < BK; k++) {
      float4 av = *(const float4*)&As[k][ty << 2];
      float4 bv = *(const float4*)&Bs[k][tx << 2];
      float a0 = av.x, a1 = av.y, a2 = av.z, a3 = av.w;
      float b0 = bv.x, b1 = bv.y, b2 = bv.z, b3 = bv.w;
      acc[0][0] += a0 * b0; acc[0][1] += a0 * b1; acc[0][2] += a0 * b2; acc[0][3] += a0 * b3;
      acc[1][0] += a1 * b0; acc[1][1] += a1 * b1; acc[1][2] += a1 * b2; acc[1][3] += a1 * b3;
      acc[2][0] += a2 * b0; acc[2][1] += a2 * b1; acc[2][2] += a2 * b2; acc[2][3] += a2 * b3;
      acc[3][0] += a3 * b0; acc[3][1] += a3 * b1; acc[3][2] += a3 * b2; acc[3][3] += a3 * b3;
    }
  }
#pragma unroll
  for (int i = 0; i < 4; i++) {
    const int row = rowBase + (ty << 2) + i;
    const int col = colBase + (tx << 2);
    float4 o;
    o.x = acc[i][0] + bias[col + 0];
    o.y = acc[i][1] + bias[col + 1];
    o.z = acc[i][2] + bias[col + 2];
    o.w = acc[i][3] + bias[col + 3];
    *(float4*)&C[(size_t)row * G4 + col] = o;
  }
}

// ---------------------------------------------------------------------------
// Gate dot-products: weights in registers, child h from LDS (broadcast).
// ---------------------------------------------------------------------------
template<int NC>
__device__ __forceinline__ void gates_lds(
    const float (*hch)[HID], int e0,
    const float4* wi, const float4* wu, const float4* wo, const float* wf,
    float& aI, float& aU, float& aO, float (&aF)[4])
{
#pragma unroll
  for (int q = 0; q < 8; q++) {
    float4 c0 = *(const float4*)&hch[0][e0 + 4 * q];
    float4 c1 = {0,0,0,0}, c2 = {0,0,0,0}, c3 = {0,0,0,0};
    if constexpr (NC > 1) c1 = *(const float4*)&hch[1][e0 + 4 * q];
    if constexpr (NC > 2) c2 = *(const float4*)&hch[2][e0 + 4 * q];
    if constexpr (NC > 3) c3 = *(const float4*)&hch[3][e0 + 4 * q];
    float sx = c0.x, sy = c0.y, sz = c0.z, sw = c0.w;
    if constexpr (NC > 1) { sx += c1.x; sy += c1.y; sz += c1.z; sw += c1.w; }
    if constexpr (NC > 2) { sx += c2.x; sy += c2.y; sz += c2.z; sw += c2.w; }
    if constexpr (NC > 3) { sx += c3.x; sy += c3.y; sz += c3.z; sw += c3.w; }
    aI += wi[q].x * sx; aI += wi[q].y * sy; aI += wi[q].z * sz; aI += wi[q].w * sw;
    aU += wu[q].x * sx; aU += wu[q].y * sy; aU += wu[q].z * sz; aU += wu[q].w * sw;
    aO += wo[q].x * sx; aO += wo[q].y * sy; aO += wo[q].z * sz; aO += wo[q].w * sw;
    aF[0] += wf[4*q+0] * c0.x; aF[0] += wf[4*q+1] * c0.y;
    aF[0] += wf[4*q+2] * c0.z; aF[0] += wf[4*q+3] * c0.w;
    if constexpr (NC > 1) {
      aF[1] += wf[4*q+0] * c1.x; aF[1] += wf[4*q+1] * c1.y;
      aF[1] += wf[4*q+2] * c1.z; aF[1] += wf[4*q+3] * c1.w;
    }
    if constexpr (NC > 2) {
      aF[2] += wf[4*q+0] * c2.x; aF[2] += wf[4*q+1] * c2.y;
      aF[2] += wf[4*q+2] * c2.z; aF[2] += wf[4*q+3] * c2.w;
    }
    if constexpr (NC > 3) {
      aF[3] += wf[4*q+0] * c3.x; aF[3] += wf[4*q+1] * c3.y;
      aF[3] += wf[4*q+2] * c3.z; aF[3] += wf[4*q+3] * c3.w;
    }
  }
}

// ---------------------------------------------------------------------------
// Fused parallel poll+stage for one node's NC children.
// Each thread batches ALL its pending loads (<=NC H + <=NC C) into one issue
// round per iteration -> detect latency = last-ready-child + ~1 LLC RT,
// independent of NC. Retired values drop straight into LDS.
// ---------------------------------------------------------------------------
template<int NC>
__device__ __forceinline__ void poll_stage(
    const int* cix, int tid, int lr,
    float (*hch)[HID], float (*chc)[32],
    const float* Hout, const float* Cout)
{
  const uint32_t* hp[NC];
  const uint32_t* cp[NC];
#pragma unroll
  for (int k = 0; k < NC; k++) {
    hp[k] = (const uint32_t*)(Hout + (size_t)cix[k] * HID + tid);
    cp[k] = (const uint32_t*)(Cout + (size_t)cix[k] * HID + tid);
  }
  unsigned hm = (1u << NC) - 1;
  unsigned cm = ((unsigned)lr < 32u) ? (1u << NC) - 1 : 0u;
  for (;;) {
    uint32_t th[NC], tc[NC];
#pragma unroll
    for (int k = 0; k < NC; k++)
      if (hm & (1u << k)) th[k] = AT_LDU(hp[k]);
#pragma unroll
    for (int k = 0; k < NC; k++)
      if (cm & (1u << k)) tc[k] = AT_LDU(cp[k]);
#pragma unroll
    for (int k = 0; k < NC; k++)
      if ((hm & (1u << k)) && th[k] != SENT) {
        hch[k][tid] = __uint_as_float(th[k]);
        hm &= ~(1u << k);
      }
#pragma unroll
    for (int k = 0; k < NC; k++)
      if ((cm & (1u << k)) && tc[k] != SENT) {
        chc[k][lr] = __uint_as_float(tc[k]);
        cm &= ~(1u << k);
      }
    if (!(hm | cm)) break;
    __builtin_amdgcn_s_sleep(1);
  }
}

// ---------------------------------------------------------------------------
// Kernel 2: persistent dataflow recurrence, flag-free, fully parallel polls.
// BOTH H and C are NaN-sentinel-initialized; consumers poll each value they
// need directly (LLC-coherent relaxed atomics), so the producer needs NO
// store ordering at all — C and H stores fly concurrently.
// ---------------------------------------------------------------------------
__global__ void __launch_bounds__(BLK, 2) recur(
    const float* __restrict__ i2h,
    const float* __restrict__ hs2h_w, const float* __restrict__ hc2h_w,
    const float* __restrict__ hs2h_b, const float* __restrict__ hc2h_b,
    const int* __restrict__ child_idx, const int* __restrict__ child_mask,
    float* Hout, float* Cout)
{
  __shared__ float hch[MAXC][HID];     // 8 KB: children h
  __shared__ float chc[MAXC][32];      // 0.5 KB: children c (this slice only)
  __shared__ float4 redA[NSUB][32];    // 8 KB: {aI,aU,aO,aF0}
  __shared__ float4 redB[NSUB][32];    // 8 KB: {aF1,aF2,aF3,-}

  const int tid = threadIdx.x;
  const int wg = blockIdx.x;
  const int team = wg & (T_TEAMS - 1);
  const int slice = wg >> 4;           // 0..15 : this wg's 32 hidden dims
  const int rr = tid & 31;
  const int sub = tid >> 5;            // 0..15 : e-chunk
  const int rp = slice * 32 + rr;
  const int e0 = sub * ECH;
  const int lr = tid - slice * 32;     // in [0,32) iff this thread stages chc

  // ---- one-time: weights into registers (128 floats/thread) ----
  float4 wi[8], wu[8], wo[8];
  float wf[32];
#pragma unroll
  for (int q = 0; q < 8; q++) {
    wi[q] = *(const float4*)&hs2h_w[(size_t)rp * HID + e0 + 4 * q];
    wu[q] = *(const float4*)&hs2h_w[(size_t)(512 + rp) * HID + e0 + 4 * q];
    wo[q] = *(const float4*)&hs2h_w[(size_t)(1024 + rp) * HID + e0 + 4 * q];
  }
#pragma unroll
  for (int e = 0; e < 32; e++)
    wf[e] = hc2h_w[(size_t)(e0 + e) * HID + rp];

  // ---- one-time: epilogue biases (wave0 / tid<32 only) ----
  const int rpp = slice * 32 + tid;    // valid only for tid<32
  float bI = 0.f, bU = 0.f, bO = 0.f, bF = 0.f;
  if (tid < 32) {
    bI = hs2h_b[rpp]; bU = hs2h_b[512 + rpp];
    bO = hs2h_b[1024 + rpp]; bF = hc2h_b[rpp];
  }

  for (int j = team; j < N_NODES; j += T_TEAMS) {
    const int4 ci = *(const int4*)&child_idx[j * 4];
    const int4 cm = *(const int4*)&child_mask[j * 4];
    const int nc = cm.x + cm.y + cm.z + cm.w;   // mask is a prefix
    const int cix[4] = {ci.x, ci.y, ci.z, ci.w};

    // prefetch i2h (plain cached loads; overlaps polling below)
    float ipre = 0.f, fpre = 0.f, upre = 0.f, opre = 0.f;
    if (tid < 32) {
      const size_t jb = (size_t)j * G4;
      ipre = i2h[jb + rpp];
      fpre = i2h[jb + 512 + rpp];
      upre = i2h[jb + 1024 + rpp];
      opre = i2h[jb + 1536 + rpp];
    }

    float aI = 0.f, aU = 0.f, aO = 0.f, aF[4] = {0.f, 0.f, 0.f, 0.f};

    if (nc > 0) {
      switch (nc) {
        case 1: poll_stage<1>(cix, tid, lr, hch, chc, Hout, Cout); break;
        case 2: poll_stage<2>(cix, tid, lr, hch, chc, Hout, Cout); break;
        case 3: poll_stage<3>(cix, tid, lr, hch, chc, Hout, Cout); break;
        default: poll_stage<4>(cix, tid, lr, hch, chc, Hout, Cout); break;
      }
      __syncthreads();  // B2: hch/chc ready

      // wave0 snapshots child c before B3 (next node's stage rewrites chc)
      float cC0 = 0.f, cC1 = 0.f, cC2 = 0.f, cC3 = 0.f;
      if (tid < 32) {
        cC0 = chc[0][tid];
        if (nc > 1) cC1 = chc[1][tid];
        if (nc > 2) cC2 = chc[2][tid];
        if (nc > 3) cC3 = chc[3][tid];
      }

      switch (nc) {
        case 1: gates_lds<1>(hch, e0, wi, wu, wo, wf, aI, aU, aO, aF); break;
        case 2: gates_lds<2>(hch, e0, wi, wu, wo, wf, aI, aU, aO, aF); break;
        case 3: gates_lds<3>(hch, e0, wi, wu, wo, wf, aI, aU, aO, aF); break;
        default: gates_lds<4>(hch, e0, wi, wu, wo, wf, aI, aU, aO, aF); break;
      }
      redA[sub][rr] = make_float4(aI, aU, aO, aF[0]);
      redB[sub][rr] = make_float4(aF[1], aF[2], aF[3], 0.f);
      __syncthreads();  // B3: red ready; hch/chc free for next node

      if (tid < 32) {
        float sI = 0.f, sU = 0.f, sO = 0.f;
        float sF0 = 0.f, sF1 = 0.f, sF2 = 0.f, sF3 = 0.f;
#pragma unroll
        for (int s = 0; s < NSUB; s++) {
          float4 a = redA[s][tid];
          float4 b = redB[s][tid];
          sI += a.x; sU += a.y; sO += a.z; sF0 += a.w;
          sF1 += b.x; sF2 += b.y; sF3 += b.z;
        }
        const float ig = ipre + bI + sI;
        const float ug = upre + bU + sU;
        const float og = opre + bO + sO;
        float c = sigm(ig) * tanhf(ug);
        c += sigm(fpre + bF + sF0) * cC0;
        if (nc > 1) c += sigm(fpre + bF + sF1) * cC1;
        if (nc > 2) c += sigm(fpre + bF + sF2) * cC2;
        if (nc > 3) c += sigm(fpre + bF + sF3) * cC3;
        const float h = sigm(og) * tanhf(c);
        // no ordering needed: C and H each carry their own sentinel
        AT_STF(Cout + (size_t)j * HID + rpp, c);
        AT_STF(Hout + (size_t)j * HID + rpp, h);
      }
    } else {
      // leaf: wave0 only, no barriers
      if (tid < 32) {
        const float c = sigm(ipre + bI) * tanhf(upre + bU);
        const float h = sigm(opre + bO) * tanhf(c);
        AT_STF(Cout + (size_t)j * HID + rpp, c);
        AT_STF(Hout + (size_t)j * HID + rpp, h);
      }
    }
  }
}

// ---------------------------------------------------------------------------
// Workspace: [0,128MB) i2h. Whole d_out (H and C) is sentinel-initialized.
// ---------------------------------------------------------------------------
extern "C" void kernel_launch(void* const* d_in, const int* in_sizes, int n_in,
                              void* d_out, int out_size, void* d_ws, size_t ws_size,
                              hipStream_t stream) {
  const float* inputs    = (const float*)d_in[0];
  const float* i2h_w     = (const float*)d_in[1];
  const float* i2h_b     = (const float*)d_in[2];
  const float* hs2h_w    = (const float*)d_in[3];
  const float* hs2h_b    = (const float*)d_in[4];
  const float* hc2h_w    = (const float*)d_in[5];
  const float* hc2h_b    = (const float*)d_in[6];
  const int*   child_idx = (const int*)d_in[7];
  const int*   child_mask= (const int*)d_in[8];

  float* Hout = (float*)d_out;
  float* Cout = Hout + (size_t)N_NODES * HID;

  float* i2h = (float*)d_ws;

  // H and C -> 0xFFFFFFFF = NaN sentinel (computed h,c always finite)
  hipMemsetAsync(d_out, 0xFF, (size_t)2 * N_NODES * HID * sizeof(float), stream);

  dim3 ggrid(G4 / 64, N_NODES / 64);
  gemm_i2h<<<ggrid, 256, 0, stream>>>(inputs, i2h_w, i2h_b, i2h);
  recur<<<NWG, BLK, 0, stream>>>(i2h, hs2h_w, hc2h_w, hs2h_b, hc2h_b,
                                 child_idx, child_mask, Hout, Cout);
}